// Round 8
// baseline (43.573 us; speedup 1.0000x reference)
//
#include <hip/hip_runtime.h>
#include <hip/hip_cooperative_groups.h>

namespace coop = cooperative_groups;

// out[b,n,d] = (x@Wq+bq)[b,n,d] * kv[b,d],  kv[b,d] = sum_m ((x@Wk+bk)*(x@Wv+bv))[b,m,d]
// B=4, N=1024, D=128, fp32 in/out.
//
// R8 = R7's proj engine (MFMA bf16x3, 13.0us) FUSED into one cooperative
// kernel. R7's residual ~5-7us was serialization overhead: 2 dependent
// launches + q round-trip (2MB wr + 2MB rd + 2MB wr). Now: q stays in
// registers across grid.sync(); kv partials -> ws -> fixed-order reduce;
// out written once. Scale kernel and second launch gone.
//  - grid 256 = cgi(4, high) x rt(64), 512 thr (8 waves = 4 row x 2 col
//    subtiles of 16x16). LDS 80 KB -> 2 blocks/CU capacity >= coop needs.
//  - staging: v_cvt_pk_bf16_f32 RNE hi/lo split (w = hi+lo), swizzled 16B
//    slices; terms Ah*Bh + Al*Bh + Ah*Bl. A and B share the k-permutation
//    (cancels); C/D map col=lane&15, row=(lane>>4)*4+reg (HW-verified).
//  - partials: rowgroup rg = rt*4+wr (16 rows), 256 x 128 floats in ws;
//    every slot read post-sync is written pre-sync this iteration (no
//    dependence on ws initial contents).

#define NN 1024
#define DD 128

typedef __attribute__((ext_vector_type(8))) short short8;
typedef __attribute__((ext_vector_type(4))) float f32x4;

union Frag { short8 s; unsigned int u[4]; };

static __device__ __forceinline__ unsigned int cvtpk(float a, float b) {
    unsigned int r;
    asm("v_cvt_pk_bf16_f32 %0, %1, %2" : "=v"(r) : "v"(a), "v"(b));
    return r;   // low16 = bf16(a), high16 = bf16(b)
}

static __device__ __forceinline__ void split2(float a, float b,
                                              unsigned int& hp, unsigned int& lp) {
    hp = cvtpk(a, b);
    const float ha = __uint_as_float(hp << 16);
    const float hb = __uint_as_float(hp & 0xFFFF0000u);
    lp = cvtpk(a - ha, b - hb);
}

__global__ __launch_bounds__(512, 2) void fused_kernel(
    const float* __restrict__ x,
    const float* __restrict__ Wq, const float* __restrict__ bq,
    const float* __restrict__ Wk, const float* __restrict__ bk,
    const float* __restrict__ Wv, const float* __restrict__ bv,
    float* __restrict__ out, float* __restrict__ ws)
{
    __shared__ __align__(16) unsigned short xh[64][DD];        // 16 KB
    __shared__ __align__(16) unsigned short xl[64][DD];        // 16 KB
    __shared__ __align__(16) unsigned short wt[3][2][32][DD];  // 48 KB

    const int bid = blockIdx.x;          // 256 = cgi(4) x rt(64)
    const int rt  = bid & 63;            // rows rt*64 .. rt*64+63
    const int cgi = bid >> 6;            // cols cgi*32 .. cgi*32+31
    const int tid = threadIdx.x;
    const int cbase = cgi << 5;
    const int b = rt >> 4;               // batch of this row tile

    // ---- stage W slab: thread owns (col, k-octet) ----
    {
        const int col = tid & 31;
        const int ko  = (tid >> 5) & 15;             // k = 8*ko .. 8*ko+7
        const int swz = (ko ^ (col & 7)) << 4;
#pragma unroll
        for (int m = 0; m < 3; ++m) {
            const float* wp = m == 0 ? Wq : (m == 1 ? Wk : Wv);
            const float* src = wp + (size_t)(ko << 3) * DD + cbase + col;
            float e[8];
#pragma unroll
            for (int i = 0; i < 8; ++i) e[i] = src[(size_t)i * DD];
            unsigned int hp[4], lp[4];
#pragma unroll
            for (int j = 0; j < 4; ++j) split2(e[2*j], e[2*j+1], hp[j], lp[j]);
            *reinterpret_cast<int4*>((char*)&wt[m][0][col][0] + swz) =
                *reinterpret_cast<int4*>(hp);
            *reinterpret_cast<int4*>((char*)&wt[m][1][col][0] + swz) =
                *reinterpret_cast<int4*>(lp);
        }
    }

    // ---- stage x tile [64 rows][128 k] as hi/lo planes ----
    {
        const float4* src = reinterpret_cast<const float4*>(x + (size_t)rt * 64 * DD);
#pragma unroll
        for (int j = 0; j < 4; ++j) {
            const int idx = tid + j * 512;           // 0..2047 float4s, coalesced
            const float4 v = src[idx];
            const int row = idx >> 5, c4 = idx & 31;
            const int s = c4 >> 1, half = c4 & 1;
            const int off = ((s ^ (row & 7)) << 4) + (half << 3);
            unsigned int h0, l0, h1, l1;
            split2(v.x, v.y, h0, l0);
            split2(v.z, v.w, h1, l1);
            const unsigned long long hp =
                (unsigned long long)h0 | ((unsigned long long)h1 << 32);
            const unsigned long long lp =
                (unsigned long long)l0 | ((unsigned long long)l1 << 32);
            *reinterpret_cast<unsigned long long*>((char*)&xh[row][0] + off) = hp;
            *reinterpret_cast<unsigned long long*>((char*)&xl[row][0] + off) = lp;
        }
    }
    __syncthreads();

    // ---- MFMA: wave (wr 0..3, wc 0..1) -> one 16x16 tile of q,k,v ----
    const int lane  = tid & 63;
    const int w8    = tid >> 6;
    const int wr    = w8 >> 1;
    const int wc    = w8 & 1;
    const int lr    = lane & 15;
    const int kslot = lane >> 4;
    const int arow  = (wr << 4) + lr;     // 0..63
    const int bcol  = (wc << 4) + lr;     // 0..31

    f32x4 qa = {0.f, 0.f, 0.f, 0.f};
    f32x4 ka = {0.f, 0.f, 0.f, 0.f};
    f32x4 va = {0.f, 0.f, 0.f, 0.f};

    const char* xhp = (const char*)&xh[arow][0];
    const char* xlp = (const char*)&xl[arow][0];
    const int   aswz = arow & 7;
    const char* wb   = (const char*)&wt[0][0][bcol][0];
    const int   bswz = bcol & 7;
    const int   MATS = 2 * 32 * DD * 2;   // bytes per mat
    const int   HS   = 32 * DD * 2;       // bytes per hi/lo plane

#pragma unroll
    for (int ks = 0; ks < 4; ++ks) {
        const int s   = (ks << 2) + kslot;            // 16B slice 0..15
        const int aof = (s ^ aswz) << 4;
        const int bof = (s ^ bswz) << 4;
        Frag ah, al, qh, ql, kh, kl, vh, vl;
        ah.s = *reinterpret_cast<const short8*>(xhp + aof);
        al.s = *reinterpret_cast<const short8*>(xlp + aof);
        qh.s = *reinterpret_cast<const short8*>(wb + bof);
        ql.s = *reinterpret_cast<const short8*>(wb + HS + bof);
        kh.s = *reinterpret_cast<const short8*>(wb + MATS + bof);
        kl.s = *reinterpret_cast<const short8*>(wb + MATS + HS + bof);
        vh.s = *reinterpret_cast<const short8*>(wb + 2 * MATS + bof);
        vl.s = *reinterpret_cast<const short8*>(wb + 2 * MATS + HS + bof);

        qa = __builtin_amdgcn_mfma_f32_16x16x32_bf16(ah.s, qh.s, qa, 0, 0, 0);
        qa = __builtin_amdgcn_mfma_f32_16x16x32_bf16(al.s, qh.s, qa, 0, 0, 0);
        qa = __builtin_amdgcn_mfma_f32_16x16x32_bf16(ah.s, ql.s, qa, 0, 0, 0);

        ka = __builtin_amdgcn_mfma_f32_16x16x32_bf16(ah.s, kh.s, ka, 0, 0, 0);
        ka = __builtin_amdgcn_mfma_f32_16x16x32_bf16(al.s, kh.s, ka, 0, 0, 0);
        ka = __builtin_amdgcn_mfma_f32_16x16x32_bf16(ah.s, kl.s, ka, 0, 0, 0);

        va = __builtin_amdgcn_mfma_f32_16x16x32_bf16(ah.s, vh.s, va, 0, 0, 0);
        va = __builtin_amdgcn_mfma_f32_16x16x32_bf16(al.s, vh.s, va, 0, 0, 0);
        va = __builtin_amdgcn_mfma_f32_16x16x32_bf16(ah.s, vl.s, va, 0, 0, 0);
    }

    // ---- kv partial for this wave's 16 rows -> ws (pre-sync) ----
    const int colg = cbase + (wc << 4) + lr;
    const float bqc = bq[colg], bkc = bk[colg], bvc = bv[colg];

    float p = 0.f;
#pragma unroll
    for (int i = 0; i < 4; ++i)
        p += (ka[i] + bkc) * (va[i] + bvc);
    p += __shfl_xor(p, 16);
    p += __shfl_xor(p, 32);
    if (lane < 16)
        ws[(size_t)((rt << 2) + wr) * DD + colg] = p;   // rg = rt*4+wr

    coop::this_grid().sync();

    // ---- kv = fixed-order sum of this batch's 64 rowgroups; scale q ----
    float kvc = 0.f;
    {
        const float* pp = ws + (size_t)b * 64 * DD + colg;
#pragma unroll
        for (int j = 0; j < 64; ++j) kvc += pp[(size_t)j * DD];
    }
    const size_t rbase = ((size_t)rt * 64 + (wr << 4) + (kslot << 2)) * DD + colg;
#pragma unroll
    for (int i = 0; i < 4; ++i)
        out[rbase + (size_t)i * DD] = (qa[i] + bqc) * kvc;
}

extern "C" void kernel_launch(void* const* d_in, const int* in_sizes, int n_in,
                              void* d_out, int out_size, void* d_ws, size_t ws_size,
                              hipStream_t stream) {
    const float* x  = (const float*)d_in[0];
    const float* Wq = (const float*)d_in[1];
    const float* bq = (const float*)d_in[2];
    const float* Wk = (const float*)d_in[3];
    const float* bk = (const float*)d_in[4];
    const float* Wv = (const float*)d_in[5];
    const float* bv = (const float*)d_in[6];
    float* out      = (float*)d_out;
    float* ws       = (float*)d_ws;   // 256 rowgroups x 128 = 128 KB

    void* args[] = {(void*)&x, (void*)&Wq, (void*)&bq, (void*)&Wk, (void*)&bk,
                    (void*)&Wv, (void*)&bv, (void*)&out, (void*)&ws};
    hipLaunchCooperativeKernel((const void*)fused_kernel, dim3(256), dim3(512),
                               args, 0, stream);
}